// Round 4
// baseline (171.830 us; speedup 1.0000x reference)
//
#include <hip/hip_runtime.h>
#include <math.h>

typedef float2 c32;

__device__ __forceinline__ c32 cmulc(c32 a, c32 b){
    return make_float2(fmaf(a.x, b.x, -(a.y*b.y)), fmaf(a.x, b.y, a.y*b.x));
}
__device__ __forceinline__ c32 caddc(c32 a, c32 b){ return make_float2(a.x+b.x, a.y+b.y); }
__device__ __forceinline__ c32 csubc(c32 a, c32 b){ return make_float2(a.x-b.x, a.y-b.y); }

// In-register DIT FFT of size N (8 or 16), natural-order in/out.
// tw[m] = e^{sign*2*pi*i*m/16}  (sign baked into the table the caller built).
template<int N>
__device__ __forceinline__ void fftN(c32* a, const c32* tw){
    constexpr int LOG = (N == 16) ? 4 : 3;
    c32 b[N];
    #pragma unroll
    for (int i = 0; i < N; ++i){
        int r = 0;
        #pragma unroll
        for (int bb = 0; bb < LOG; ++bb) r = (r << 1) | ((i >> bb) & 1);
        b[i] = a[r];
    }
    #pragma unroll
    for (int len = 2; len <= N; len <<= 1){
        #pragma unroll
        for (int i = 0; i < N; i += len){
            #pragma unroll
            for (int j = 0; j < len/2; ++j){
                c32 t = b[i + j + len/2];
                if (j) t = cmulc(tw[j * (16/len)], t);
                c32 u = b[i + j];
                b[i + j]         = caddc(u, t);
                b[i + j + len/2] = csubc(u, t);
            }
        }
    }
    #pragma unroll
    for (int i = 0; i < N; ++i) a[i] = b[i];
}

// ---------------------------------------------------------------------------
// 1) conv3x3 stride2 SAME + gelu + partial spatial sums (deterministic)
//    Single-wave blocks: grid = (B*T)*32, 64 thr. Block = 2 output rows.
//    Slab [5][388] row-major; 2-output-position pairs read 3x4 ds_read_b128.
//    Thread owns 4 channels (27 float4 weights in VGPRs) x 16 positions.
//    part[(bt*32+rp)*32 + c] = sum over 128 positions of gelu(conv)
// ---------------------------------------------------------------------------
__global__ __launch_bounds__(64) void k_conv(const float* __restrict__ in,
                                             const float* __restrict__ cw,
                                             const float* __restrict__ cb,
                                             float* __restrict__ part)
{
    __shared__ float xs[5 * 388];          // rows r0..r0+4, cols 0..387 (>=384 pad)
    const int tid = threadIdx.x;           // 0..63
    const int bt = blockIdx.x >> 5, rp = blockIdx.x & 31;
    const int r0 = 4 * rp;                 // first input row of the slab

    // per-thread weights first (independent of LDS)
    const int cg4 = (tid & 7) * 4;         // channel base (4 channels)
    const int pq  = tid >> 3;              // 0..7 position-pair lane group
    float4 w[27];
    #pragma unroll
    for (int q = 0; q < 27; ++q) w[q] = *(const float4*)&cw[q * 32 + cg4];
    const float4 b4 = *(const float4*)&cb[cg4];

    // stage slab (coalesced; zero pad x>=128 cols and rows past bottom)
    const float* src = in + (size_t)bt * 49152 + (size_t)r0 * 384;
    for (int i = tid; i < 5 * 388; i += 64){
        int r = i / 388, col = i - r * 388;
        float v = 0.0f;
        if (col < 384 && (r0 + r) < 128) v = src[r * 384 + col];
        xs[r * 388 + col] = v;
    }
    __syncthreads();

    float a0 = 0.f, a1 = 0.f, a2 = 0.f, a3 = 0.f;

    #pragma unroll
    for (int it = 0; it < 8; ++it){
        const int oy  = it & 1;                    // local output row 0..1
        const int oxp = pq + ((it >> 1) << 3);     // position pair 0..31
        // output positions ox = 2*oxp, 2*oxp+1 ; taps cols 12*oxp .. 12*oxp+14
        float sA0 = b4.x, sA1 = b4.y, sA2 = b4.z, sA3 = b4.w;
        float sB0 = b4.x, sB1 = b4.y, sB2 = b4.z, sB3 = b4.w;
        #pragma unroll
        for (int ky = 0; ky < 3; ++ky){
            const float4* rb = (const float4*)&xs[(2*oy + ky) * 388 + 12 * oxp];
            float f[16];
            *(float4*)&f[0]  = rb[0];
            *(float4*)&f[4]  = rb[1];
            *(float4*)&f[8]  = rb[2];
            *(float4*)&f[12] = rb[3];
            #pragma unroll
            for (int m = 0; m < 9; ++m){
                const float4 wq = w[ky * 9 + m];
                sA0 = fmaf(f[m],     wq.x, sA0);
                sA1 = fmaf(f[m],     wq.y, sA1);
                sA2 = fmaf(f[m],     wq.z, sA2);
                sA3 = fmaf(f[m],     wq.w, sA3);
                sB0 = fmaf(f[m + 6], wq.x, sB0);
                sB1 = fmaf(f[m + 6], wq.y, sB1);
                sB2 = fmaf(f[m + 6], wq.z, sB2);
                sB3 = fmaf(f[m + 6], wq.w, sB3);
            }
        }
        // gelu via fast tanh: tanh(u) = 1 - 2/(1+e^{2u}); exp2/rcp HW ops
        #define GELU_ACC(S, A)                                                      \
        {                                                                           \
            float u_ = 0.7978845608028654f * fmaf(0.044715f * (S), (S)*(S), (S));   \
            float e_ = __builtin_amdgcn_exp2f(2.8853900817779268f * u_);            \
            float t_ = 1.0f - 2.0f * __builtin_amdgcn_rcpf(1.0f + e_);              \
            (A) += 0.5f * (S) * (1.0f + t_);                                        \
        }
        GELU_ACC(sA0, a0) GELU_ACC(sA1, a1) GELU_ACC(sA2, a2) GELU_ACC(sA3, a3)
        GELU_ACC(sB0, a0) GELU_ACC(sB1, a1) GELU_ACC(sB2, a2) GELU_ACC(sB3, a3)
        #undef GELU_ACC
    }

    // reduce over the 8 lane-groups (lanes cg, cg+8, ..., cg+56)
    #pragma unroll
    for (int off = 32; off >= 8; off >>= 1){
        a0 += __shfl_down(a0, off, 64);
        a1 += __shfl_down(a1, off, 64);
        a2 += __shfl_down(a2, off, 64);
        a3 += __shfl_down(a3, off, 64);
    }
    if (tid < 8){
        float4* dst = (float4*)&part[(size_t)blockIdx.x * 32 + tid * 4];
        *dst = make_float4(a0, a1, a2, a3);
    }
}

// ---------------------------------------------------------------------------
// 2) gates: ctx mean -> alpha/delta (sigmoid), mu/gamma (softplus). 384 thr.
// ---------------------------------------------------------------------------
__global__ __launch_bounds__(64) void k_gates(const float* __restrict__ part,
    const float* __restrict__ wA, const float* __restrict__ bA,
    const float* __restrict__ wD, const float* __restrict__ bD,
    const float* __restrict__ wM, const float* __restrict__ bM,
    const float* __restrict__ wG, const float* __restrict__ bG,
    float* __restrict__ gA, float* __restrict__ gD,
    float* __restrict__ gM, float* __restrict__ gG)
{
    int g = blockIdx.x * 64 + threadIdx.x;
    if (g >= 384) return;
    int bt = g / 3, c = g % 3;
    float sA = bA[c], sD = bD[c], sM = bM[c], sG = bG[c];
    for (int j = 0; j < 32; ++j){
        float cs = 0.f;
        #pragma unroll
        for (int q = 0; q < 32; ++q) cs += part[(bt*32 + q)*32 + j];
        cs *= (1.0f / 4096.0f);
        sA = fmaf(cs, wA[j*3+c], sA);
        sD = fmaf(cs, wD[j*3+c], sD);
        sM = fmaf(cs, wM[j*3+c], sM);
        sG = fmaf(cs, wG[j*3+c], sG);
    }
    gA[g] = 1.0f / (1.0f + expf(-sA));
    gD[g] = 1.0f / (1.0f + expf(-sD));
    gM[g] = fmaxf(sM, 0.f) + log1pf(expf(-fabsf(sM)));
    gG[g] = fmaxf(sG, 0.f) + log1pf(expf(-fabsf(sG)));
}

// ---------------------------------------------------------------------------
// 3) spectral kernels: KE/KI[c][u][v] = rfft2(pad(k, 56)) via direct 256-tap DFT
// ---------------------------------------------------------------------------
__global__ __launch_bounds__(256) void k_spectral(const float* __restrict__ k_exc,
                                                  const float* __restrict__ k_inh,
                                                  float* __restrict__ KEw,
                                                  float* __restrict__ KIw)
{
    __shared__ c32 Wt[128];
    int tid = threadIdx.x;
    if (tid < 128){
        float ang = -0.049087385212340517f * (float)tid;   // -2*pi*t/128
        float s, co; sincosf(ang, &s, &co);
        Wt[tid] = make_float2(co, s);
    }
    __syncthreads();
    int g = blockIdx.x * 256 + tid;
    if (g >= 2 * 24960) return;
    int which = g / 24960, r = g % 24960;
    int c = r / 8320, uv = r % 8320;
    int u_ = uv / 65, v_ = uv % 65;
    const float* kk = which ? k_inh : k_exc;
    float ar = 0.f, ai = 0.f;
    for (int y = 0; y < 16; ++y){
        int pu = u_ * (56 + y);
        #pragma unroll
        for (int x = 0; x < 16; ++x){
            int idx = (pu + v_ * (56 + x)) & 127;
            float kv = kk[(y*16 + x)*3 + c];
            c32 w = Wt[idx];
            ar = fmaf(kv, w.x, ar);
            ai = fmaf(kv, w.y, ai);
        }
    }
    ((float2*)(which ? KIw : KEw))[c*8320 + uv] = make_float2(ar, ai);
}

// ---------------------------------------------------------------------------
// 4) forward rfft2 per (b,t,c) image.  4-step FFT-128 = FFT8 x FFT16.
//    Row pass packs rows (2r, 2r+1) into one complex FFT.  Output
//    U_ws[bt][c][u][v] (v=0..64), complex interleaved.
// ---------------------------------------------------------------------------
__global__ __launch_bounds__(512) void k_fft_fwd(const float* __restrict__ in,
                                                 float* __restrict__ U_ws)
{
    __shared__ c32 A[8320];     // [64][130] for rows, flat [128][65] after unpack
    __shared__ c32 Bf[8320];    // [64][130] for Z rows, flat [128][65] for col out
    __shared__ c32 Wt[128];
    const int tid = threadIdx.x;
    const int img = blockIdx.x;             // bt*3 + c
    const int bt = img / 3, c = img % 3;

    if (tid < 128){
        float ang = -0.049087385212340517f * (float)tid;
        float s, co; sincosf(ang, &s, &co);
        Wt[tid] = make_float2(co, s);
    }
    __syncthreads();
    c32 tw8[8];
    #pragma unroll
    for (int m = 0; m < 8; ++m) tw8[m] = Wt[8*m];

    // pack: A[r*130+x] = in[2r][x] + i*in[2r+1][x]
    const float* src = in + (size_t)bt * 49152 + c;
    for (int p = tid; p < 64*128; p += blockDim.x){
        int r = p >> 7, x = p & 127;
        float re = src[(size_t)((2*r)   * 128 + x) * 3];
        float im = src[(size_t)((2*r+1) * 128 + x) * 3];
        A[r*130 + x] = make_float2(re, im);
    }
    __syncthreads();

    // row stage1: FFT8 over n2 (stride 16), twiddle W[n1*k2], in place
    for (int task = tid; task < 64*16; task += blockDim.x){
        int r = task >> 4, n1 = task & 15;
        c32 v[8];
        #pragma unroll
        for (int n2 = 0; n2 < 8; ++n2) v[n2] = A[r*130 + n1 + 16*n2];
        fftN<8>(v, tw8);
        #pragma unroll
        for (int k2 = 0; k2 < 8; ++k2)
            A[r*130 + n1 + 16*k2] = (k2 == 0) ? v[0] : cmulc(Wt[n1*k2], v[k2]);
    }
    __syncthreads();
    // row stage2: FFT16 over n1 (contiguous), Z[r][k2+8k1] -> Bf
    for (int task = tid; task < 64*8; task += blockDim.x){
        int r = task >> 3, k2 = task & 7;
        c32 v[16];
        #pragma unroll
        for (int n1 = 0; n1 < 16; ++n1) v[n1] = A[r*130 + 16*k2 + n1];
        fftN<16>(v, tw8);
        #pragma unroll
        for (int k1 = 0; k1 < 16; ++k1) Bf[r*130 + k2 + 8*k1] = v[k1];
    }
    __syncthreads();
    // unpack the two packed real rows: A_flat[y*65+v], y = 2r / 2r+1
    for (int task = tid; task < 64*65; task += blockDim.x){
        int r = task / 65, v_ = task % 65;
        c32 zk = Bf[r*130 + v_];
        c32 zn = Bf[r*130 + ((128 - v_) & 127)];
        A[(2*r)  *65 + v_] = make_float2(0.5f*(zk.x + zn.x),  0.5f*(zk.y - zn.y));
        A[(2*r+1)*65 + v_] = make_float2(0.5f*(zk.y + zn.y), -0.5f*(zk.x - zn.x));
    }
    __syncthreads();
    // col stage1: FFT8 over n2 (row stride 16), per column v, in place
    for (int task = tid; task < 16*65; task += blockDim.x){
        int n1 = task / 65, v_ = task % 65;
        c32 v[8];
        #pragma unroll
        for (int n2 = 0; n2 < 8; ++n2) v[n2] = A[(n1 + 16*n2)*65 + v_];
        fftN<8>(v, tw8);
        #pragma unroll
        for (int k2 = 0; k2 < 8; ++k2)
            A[(n1 + 16*k2)*65 + v_] = (k2 == 0) ? v[0] : cmulc(Wt[n1*k2], v[k2]);
    }
    __syncthreads();
    // col stage2: FFT16 over n1, final U[u][v] -> Bf flat
    for (int task = tid; task < 8*65; task += blockDim.x){
        int k2 = task / 65, v_ = task % 65;
        c32 v[16];
        #pragma unroll
        for (int n1 = 0; n1 < 16; ++n1) v[n1] = A[(16*k2 + n1)*65 + v_];
        fftN<16>(v, tw8);
        #pragma unroll
        for (int k1 = 0; k1 < 16; ++k1) Bf[(k2 + 8*k1)*65 + v_] = v[k1];
    }
    __syncthreads();
    float2* dst = ((float2*)U_ws) + (size_t)img * 8320;
    for (int p = tid; p < 8320; p += blockDim.x) dst[p] = Bf[p];
}

// ---------------------------------------------------------------------------
// 5) sequential T-scan (in place over U):  x' = 0.9a*x + (-KI*mu)*y + U,
//    y' = (KE*ga)*x + 0.9d*y ; store y' over U.
// ---------------------------------------------------------------------------
__global__ __launch_bounds__(256) void k_scan(float* __restrict__ U,
    const float* __restrict__ KEw, const float* __restrict__ KIw,
    const float* __restrict__ gA, const float* __restrict__ gD,
    const float* __restrict__ gM, const float* __restrict__ gG)
{
    int g = blockIdx.x * 256 + threadIdx.x;
    if (g >= 4*3*128*65) return;
    int b = g / 24960, r = g % 24960;
    int c = r / 8320, uv = r % 8320;
    float2 ke = ((const float2*)KEw)[c*8320 + uv];
    float2 ki = ((const float2*)KIw)[c*8320 + uv];
    float2* Up = (float2*)U;
    float xr = 0.f, xi = 0.f, yr = 0.f, yi = 0.f;
    for (int t = 0; t < 32; ++t){
        int btc = (b*32 + t)*3 + c;
        float al = 0.9f * gA[btc], de = 0.9f * gD[btc];
        float mu = gM[btc],       ga = gG[btc];
        float axr = -ki.x * mu, axi = -ki.y * mu;
        float ayr =  ke.x * ga, ayi =  ke.y * ga;
        size_t iu = (size_t)btc * 8320 + uv;
        float2 uin = Up[iu];
        float nxr = fmaf(al, xr, fmaf(axr, yr, fmaf(-axi, yi, uin.x)));
        float nxi = fmaf(al, xi, fmaf(axr, yi, fmaf( axi, yr, uin.y)));
        float nyr = fmaf(ayr, xr, fmaf(-ayi, xi, de * yr));
        float nyi = fmaf(ayr, xi, fmaf( ayi, xr, de * yi));
        Up[iu] = make_float2(nyr, nyi);
        xr = nxr; xi = nxi; yr = nyr; yi = nyi;
    }
}

// ---------------------------------------------------------------------------
// 6) inverse: per (b,t,c): column IFFT-128 (65 cols), then real irfft-128 per
//    row via half-size complex IFFT-64 (drops imag of bins 0/64 like numpy).
//    Final scale 1/8192 folds 1/128(col) * 1/64(half-size row).
// ---------------------------------------------------------------------------
__global__ __launch_bounds__(512) void k_fft_inv(const float* __restrict__ Y_ws,
                                                 float* __restrict__ out)
{
    __shared__ c32 A[8320];
    __shared__ c32 Bf[8320];
    __shared__ c32 Wt[128];                 // e^{+2 pi i t/128}
    const int tid = threadIdx.x;
    const int img = blockIdx.x;
    const int bt = img / 3, c = img % 3;

    if (tid < 128){
        float ang = 0.049087385212340517f * (float)tid;
        float s, co; sincosf(ang, &s, &co);
        Wt[tid] = make_float2(co, s);
    }
    __syncthreads();
    c32 tw8[8];
    #pragma unroll
    for (int m = 0; m < 8; ++m) tw8[m] = Wt[8*m];

    const float2* srcv = ((const float2*)Y_ws) + (size_t)img * 8320;
    for (int p = tid; p < 8320; p += blockDim.x) A[p] = srcv[p];
    __syncthreads();

    // col IFFT stage1 (in place, per column v)
    for (int task = tid; task < 16*65; task += blockDim.x){
        int n1 = task / 65, v_ = task % 65;
        c32 v[8];
        #pragma unroll
        for (int n2 = 0; n2 < 8; ++n2) v[n2] = A[(n1 + 16*n2)*65 + v_];
        fftN<8>(v, tw8);
        #pragma unroll
        for (int k2 = 0; k2 < 8; ++k2)
            A[(n1 + 16*k2)*65 + v_] = (k2 == 0) ? v[0] : cmulc(Wt[n1*k2], v[k2]);
    }
    __syncthreads();
    // col IFFT stage2 -> Bf[h][v] = row spectra (unscaled)
    for (int task = tid; task < 8*65; task += blockDim.x){
        int k2 = task / 65, v_ = task % 65;
        c32 v[16];
        #pragma unroll
        for (int n1 = 0; n1 < 16; ++n1) v[n1] = A[(16*k2 + n1)*65 + v_];
        fftN<16>(v, tw8);
        #pragma unroll
        for (int k1 = 0; k1 < 16; ++k1) Bf[(k2 + 8*k1)*65 + v_] = v[k1];
    }
    __syncthreads();
    // E/O prep per row: Z[k] = E[k] + i*O[k], k=0..63 -> A[y*65+k]
    for (int task = tid; task < 128*64; task += blockDim.x){
        int y = task >> 6, k = task & 63;
        c32 Xk = Bf[y*65 + k];
        c32 Xn = Bf[y*65 + 64 - k];
        if (k == 0){ Xk.y = 0.f; Xn.y = 0.f; }     // numpy drops imag of bins 0,64
        float Er = 0.5f*(Xk.x + Xn.x), Ei = 0.5f*(Xk.y - Xn.y);
        c32 d  = make_float2(0.5f*(Xk.x - Xn.x), 0.5f*(Xk.y + Xn.y));
        c32 O  = cmulc(Wt[k], d);                  // e^{+2 pi i k/128} * d
        A[y*65 + k] = make_float2(Er - O.y, Ei + O.x);
    }
    __syncthreads();
    // row IFFT-64 stage1: FFT8 over b at slots a+8b, twiddle e^{+2pi i a c/64}
    for (int task = tid; task < 128*8; task += blockDim.x){
        int y = task >> 3, a = task & 7;
        c32 v[8];
        #pragma unroll
        for (int b2 = 0; b2 < 8; ++b2) v[b2] = A[y*65 + a + 8*b2];
        fftN<8>(v, tw8);
        #pragma unroll
        for (int c2 = 0; c2 < 8; ++c2)
            A[y*65 + a + 8*c2] = (c2 == 0) ? v[0] : cmulc(Wt[2*a*c2], v[c2]);
    }
    __syncthreads();
    // row IFFT-64 stage2: FFT8 over a at slots 8c2+a -> Bf[y*65 + c2+8d]
    for (int task = tid; task < 128*8; task += blockDim.x){
        int y = task >> 3, c2 = task & 7;
        c32 v[8];
        #pragma unroll
        for (int a = 0; a < 8; ++a) v[a] = A[y*65 + 8*c2 + a];
        fftN<8>(v, tw8);
        #pragma unroll
        for (int d = 0; d < 8; ++d) Bf[y*65 + c2 + 8*d] = v[d];
    }
    __syncthreads();
    // emit: x[2m] = Re z, x[2m+1] = Im z, scale 1/8192
    float* dst = out + (size_t)bt * 49152 + c;
    const float sc = 1.0f / 8192.0f;
    for (int p = tid; p < 128*64; p += blockDim.x){
        int y = p >> 6, m = p & 63;
        c32 z = Bf[y*65 + m];
        dst[(size_t)((y << 7) + 2*m    ) * 3] = z.x * sc;
        dst[(size_t)((y << 7) + 2*m + 1) * 3] = z.y * sc;
    }
}

// ---------------------------------------------------------------------------
extern "C" void kernel_launch(void* const* d_in, const int* in_sizes, int n_in,
                              void* d_out, int out_size, void* d_ws, size_t ws_size,
                              hipStream_t stream)
{
    (void)in_sizes; (void)n_in; (void)out_size; (void)ws_size;
    const float* in   = (const float*)d_in[0];
    const float* cw   = (const float*)d_in[1];
    const float* cb   = (const float*)d_in[2];
    const float* wA   = (const float*)d_in[3];
    const float* bA   = (const float*)d_in[4];
    const float* wD   = (const float*)d_in[5];
    const float* bD   = (const float*)d_in[6];
    const float* wM   = (const float*)d_in[7];
    const float* bM   = (const float*)d_in[8];
    const float* wG   = (const float*)d_in[9];
    const float* bG   = (const float*)d_in[10];
    const float* kex  = (const float*)d_in[11];
    const float* kin  = (const float*)d_in[12];
    float* out = (float*)d_out;
    float* ws  = (float*)d_ws;

    float* part = ws;                    // 128*32*32          = 131072
    float* gA   = ws + 131072;           // 384
    float* gD   = gA + 384;
    float* gM   = gD + 384;
    float* gG   = gM + 384;              // ends 132608
    float* KEw  = ws + 132608;           // 3*128*65*2         = 49920
    float* KIw  = KEw + 49920;           // ends 232448
    float* U    = ws + 232448;           // 128*3*128*65*2     = 6389760 (in-place scan)

    k_conv    <<<dim3(4096), dim3(64),  0, stream>>>(in, cw, cb, part);
    k_gates   <<<dim3(6),    dim3(64),  0, stream>>>(part, wA, bA, wD, bD, wM, bM, wG, bG,
                                                     gA, gD, gM, gG);
    k_spectral<<<dim3(195),  dim3(256), 0, stream>>>(kex, kin, KEw, KIw);
    k_fft_fwd <<<dim3(384),  dim3(512), 0, stream>>>(in, U);
    k_scan    <<<dim3(390),  dim3(256), 0, stream>>>(U, KEw, KIw, gA, gD, gM, gG);
    k_fft_inv <<<dim3(384),  dim3(512), 0, stream>>>(U, out);
}